// Round 7
// baseline (5573.526 us; speedup 1.0000x reference)
//
#include <hip/hip_runtime.h>
#include <math.h>

#pragma clang fp contract(off)

#define BB 64      // batch
#define N_IN 64
#define N_E 256
#define N_I 64
#define N_OUT 10

__device__ inline unsigned long long rfl64(unsigned long long x) {
  unsigned int lo = __builtin_amdgcn_readfirstlane((unsigned int)x);
  unsigned int hi = __builtin_amdgcn_readfirstlane((unsigned int)(x >> 32));
  return (((unsigned long long)hi) << 32) | (unsigned long long)lo;
}

// r18 = r15 (verified 4762us) + SINGLE-WAIT FAST PATH:
//  When popcount(mE) <= 8 (typical ~5; observed always <20), decode the E
//  pointers AND speculatively decode kie pointers from the early-probed mI
//  data, issue ALL LDS reads back-to-back, and take ONE lgkm wait instead of
//  two serial {read->wait} rounds. The tag check (after publish, as in r15)
//  confirms freshness; on a stale probe the speculative values are discarded
//  and r15's exact poll+serial-gather fallback runs. Bit-exact:
//   - E fast path ≡ one batch-8 round (same order, zero-row pads +0.0f).
//   - kie 16 adds ≡ two batch-8 rounds; popc<=8 -> last 8 are exact +0.0f;
//     popc>16 -> serial continuation on the leftover mask, same order.
//  kie fallback stays batch-8 (r17's batch-16 cost ~64cy/step = +255us).
//  Wave4 keeps r17's publish-early (neutral alone; raises spec-hit rate).
__global__ __launch_bounds__(320, 1) void ping_kernel(
    const float* __restrict__ g_in,   // [T,64,64]
    const float* __restrict__ g_W0,   // [64,256]  clamp >=0 at use
    const float* __restrict__ g_W1,   // [256,10]  clamp >=0 at stage
    const float* __restrict__ g_Wee,  // [256,256]
    const float* __restrict__ g_Wei,  // [256,64]
    const float* __restrict__ g_Wie,  // [64,256]
    float* __restrict__ g_out,        // [64,10]
    int T, float dA, float dG)
{
  const int tid  = threadIdx.x;              // 0..319
  const int lane = tid & 63;
  const int wav  = tid >> 6;                 // 0..4
  const int b    = blockIdx.x;
  const int col  = (lane < N_OUT) ? lane : 0;
  const int colO = 64 + col;                 // W1 column inside merged row
  const int base64 = wav * 64;               // valid for wav<4

  __shared__ float sWie[N_I * N_E];          // 64 KB  [j][e]
  __shared__ float sWeiO[N_E * 80];          // 80 KB  [j][0:64)=Wei, [64:74)=W1
  __shared__ float sZeroRow[256];            // 1 KB zero row
  __shared__ __align__(16) float sPK[2][64][4];   // E->I partials [slot][lane][wave]
  __shared__ __align__(16) float sKoT[2][16][4];  // E->O partials [slot][col][wave]
  __shared__ __align__(16) unsigned sTag[2][4];   // partial tags (16B quads)
  __shared__ __align__(8) unsigned long long sMI[2];  // mI value per slot
  __shared__ unsigned sMITag[2];                      // mI tag per slot
  __shared__ unsigned long long sME[2][4];   // E masks (wee fallback only)
  __shared__ int sWee;

  // ---- one-time staging (320 threads) ----
  {
    const float4* s0 = (const float4*)g_Wie; float4* d0 = (float4*)sWie;
    for (int k = tid; k < (N_I * N_E) / 4; k += 320) d0[k] = s0[k];
    const float4* wei4 = (const float4*)g_Wei;         // [256][16] float4 view
    for (int k = tid; k < 256 * 16; k += 320) {
      int r = k >> 4, c4 = k & 15;
      *(float4*)&sWeiO[r * 80 + c4 * 4] = wei4[k];
    }
    for (int k = tid; k < 256 * N_OUT; k += 320) {
      int r = k / N_OUT, o = k - r * N_OUT;
      sWeiO[r * 80 + 64 + o] = fmaxf(g_W1[k], 0.f);
    }
    for (int k = tid; k < 256 * 6; k += 320) {
      int r = k / 6, c = k - r * 6;
      sWeiO[r * 80 + 74 + c] = 0.f;
    }
    for (int k = tid; k < 256; k += 320) sZeroRow[k] = 0.f;
  }
  if (tid < 8) sTag[tid >> 2][tid & 3] = 0u;
  if (tid < 8) sME[tid >> 2][tid & 3] = 0ull;
  if (tid < 2) { sMI[tid] = 0ull; sMITag[tid] = 0u; }
  if (tid == 0) sWee = 0;
  __syncthreads();
  // detect all-zero W_ee (true for this data; skipping a zero matmul is fp-exact)
  {
    bool any = false;
    const float4* p = (const float4*)g_Wee;
    for (int k = tid; k < (N_E * N_E) / 4; k += 320) {
      float4 x = p[k];
      any |= (x.x != 0.f) | (x.y != 0.f) | (x.z != 0.f) | (x.w != 0.f);
    }
    if (any) sWee = 1;   // benign race: all writers store 1
  }
  __syncthreads();
  const int wee = sWee;

  // ---- per-role state ----
  float vE = -65.f, ge = 0.f, gi = 0.f; int rE = 0;     // E neuron = tid (wav<4)
  unsigned long long mE = 0ull;                          // own E word, s_e(t-1)
  float vI = -65.f, gI = 0.f; int rI = 0;               // I neuron = lane
  unsigned long long mI = 0ull;                          // s_i(t-1)
  float vO = -65.f, gO = 0.f, accO = 0.f; int rO = 0;   // output (replicated)

  // input + W0 prefetch pipeline (producers only)
  float cur = 0.f, n1 = 0.f;
  unsigned long long mInC = 0ull, aRemC = 0ull;
  bool vaC[4] = {false, false, false, false};
  float fwC[4];
  if (wav < 4) {
    cur = g_in[b * N_IN + lane];
    n1  = g_in[((T > 1 ? 1 : 0) * BB + b) * N_IN + lane];
    mInC = __ballot(cur != 0.f);
    if (mInC) {
      unsigned long long a = mInC;
      int ja[4];
#pragma unroll
      for (int k = 0; k < 4; ++k) {
        vaC[k] = (a != 0ull); ja[k] = vaC[k] ? (__ffsll(a) - 1) : 0; a &= (a - 1ull);
      }
      aRemC = a;
#pragma unroll
      for (int k = 0; k < 4; ++k) fwC[k] = g_W0[ja[k] * N_E + tid];
    }
  }

  if (wav < 4) {
    if (!wee) {
      // ================= PRODUCER HOT LOOP =================
      for (int t = 0; t < T; ++t) {
        const int slot = t & 1;
        const int slotP = (t + 1) & 1;       // slot holding mI(t-1)
        // early probe for mI(t-1): tag THEN data (both volatile, in-order DS)
        unsigned tgP = *((volatile unsigned*)&sMITag[slotP]);
        unsigned long long mdP = *((volatile unsigned long long*)&sMI[slotP]);

        const int tp = (t + 2 < T) ? (t + 2) : (T - 1);
        float n2 = g_in[(tp * BB + b) * N_IN + lane];   // prefetch t+2

        float pEI = 0.f, kow = 0.f, kie = 0.f;

        unsigned long long e0 = mE;
        if (__popcll(e0) <= 8) {
          // ---------- FAST PATH: one merged LDS wait ----------
          // decode 8 E pointers (== one batch-8 round, zero-row padded)
          const float* qb[8];
          {
            unsigned long long e = e0;
#pragma unroll
            for (int k = 0; k < 8; ++k) {
              bool v = (e != 0ull); int j = v ? (__ffsll(e) - 1) : 0; e &= (e - 1ull);
              qb[k] = v ? &sWeiO[(base64 + j) * 80] : sZeroRow;
            }
          }
          // speculatively decode 16 kie pointers from probed mI data
          const float* pb[16];
          unsigned long long cRem;
          {
            unsigned long long c = mdP;
#pragma unroll
            for (int k = 0; k < 16; ++k) {
              bool v = (c != 0ull); int j = v ? (__ffsll(c) - 1) : 0; c &= (c - 1ull);
              pb[k] = v ? &sWie[j * N_E] : sZeroRow;
            }
            cRem = c;
          }
          // issue ALL reads back-to-back; first use below takes ONE wait
          float fq[8], fr[8], fI[16];
#pragma unroll
          for (int k = 0; k < 8; ++k) { fq[k] = qb[k][lane]; fr[k] = qb[k][colO]; }
#pragma unroll
          for (int k = 0; k < 16; ++k) fI[k] = pb[k][tid];
#pragma unroll
          for (int k = 0; k < 8; ++k) pEI += fq[k];
#pragma unroll
          for (int k = 0; k < 8; ++k) kow += fr[k];

          // publish partials, then tag (DS in-order; compiler barrier only)
          sPK[slot][lane][wav] = pEI;
          if (lane < 16) sKoT[slot][lane][wav] = kow;
          asm volatile("" ::: "memory");
          if (lane == 0) *((volatile unsigned*)&sTag[slot][wav]) = (unsigned)(t + 1);

          // resolve kie
          if (tgP == (unsigned)t) {
            // fresh: fI already holds the right rows (== two batch-8 rounds)
#pragma unroll
            for (int k = 0; k < 16; ++k) kie += fI[k];
            while (cRem) {            // popc>16 continuation, same order (rare)
              const float* pc[8];
#pragma unroll
              for (int k = 0; k < 8; ++k) {
                bool v = (cRem != 0ull); int j = v ? (__ffsll(cRem) - 1) : 0; cRem &= (cRem - 1ull);
                pc[k] = v ? &sWie[j * N_E] : sZeroRow;
              }
              float fc[8];
#pragma unroll
              for (int k = 0; k < 8; ++k) fc[k] = pc[k][tid];
#pragma unroll
              for (int k = 0; k < 8; ++k) kie += fc[k];
            }
          } else {
            // stale: poll, re-read, full recompute (r15 exact path)
            volatile unsigned* vt = (volatile unsigned*)&sMITag[slotP];
            while (*vt != (unsigned)t) {}
            asm volatile("" ::: "memory");
            unsigned long long mIc = *((volatile unsigned long long*)&sMI[slotP]);
            kie = 0.f;
            while (mIc) {
              const float* pc[8];
#pragma unroll
              for (int k = 0; k < 8; ++k) {
                bool v = (mIc != 0ull); int j = v ? (__ffsll(mIc) - 1) : 0; mIc &= (mIc - 1ull);
                pc[k] = v ? &sWie[j * N_E] : sZeroRow;
              }
              float fc[8];
#pragma unroll
              for (int k = 0; k < 8; ++k) fc[k] = pc[k][tid];
#pragma unroll
              for (int k = 0; k < 8; ++k) kie += fc[k];
            }
          }
        } else {
          // ---------- SLOW PATH: r15 verbatim ----------
          {
            unsigned long long e = e0;
            while (e) {
              const float* qb[8];
#pragma unroll
              for (int k = 0; k < 8; ++k) {
                bool v = (e != 0ull); int j = v ? (__ffsll(e) - 1) : 0; e &= (e - 1ull);
                qb[k] = v ? &sWeiO[(base64 + j) * 80] : sZeroRow;
              }
              float fq[8], fr[8];
#pragma unroll
              for (int k = 0; k < 8; ++k) { fq[k] = qb[k][lane]; fr[k] = qb[k][colO]; }
#pragma unroll
              for (int k = 0; k < 8; ++k) pEI += fq[k];
#pragma unroll
              for (int k = 0; k < 8; ++k) kow += fr[k];
            }
          }
          sPK[slot][lane][wav] = pEI;
          if (lane < 16) sKoT[slot][lane][wav] = kow;
          asm volatile("" ::: "memory");
          if (lane == 0) *((volatile unsigned*)&sTag[slot][wav]) = (unsigned)(t + 1);

          unsigned long long mIc;
          if (tgP == (unsigned)t) {
            mIc = mdP;
          } else {
            volatile unsigned* vt = (volatile unsigned*)&sMITag[slotP];
            while (*vt != (unsigned)t) {}
            asm volatile("" ::: "memory");
            mIc = *((volatile unsigned long long*)&sMI[slotP]);
          }
          while (mIc) {
            const float* pc[8];
#pragma unroll
            for (int k = 0; k < 8; ++k) {
              bool v = (mIc != 0ull); int j = v ? (__ffsll(mIc) - 1) : 0; mIc &= (mIc - 1ull);
              pc[k] = v ? &sWie[j * N_E] : sZeroRow;
            }
            float fc[8];
#pragma unroll
            for (int k = 0; k < 8; ++k) fc[k] = pc[k][tid];
#pragma unroll
            for (int k = 0; k < 8; ++k) kie += fc[k];
          }
        }

        // ---- W0 consume (prefetched last iter; ascending) ----
        float kin = 0.f;
        if (mInC) {
#pragma unroll
          for (int k = 0; k < 4; ++k) kin += vaC[k] ? fmaxf(fwC[k], 0.f) : 0.f;
          while (aRemC) {
            int j = __ffsll(aRemC) - 1; aRemC &= (aRemC - 1ull);
            kin += fmaxf(g_W0[j * N_E + tid], 0.f);
          }
        }

        // ---- E LIF (COBA, C_m=1, g_L=0.05, ref=12) -> mE(t) ----
        ge = (ge + kin) * dA;           // kee == 0 exactly (wee false)
        gi = (gi + kie) * dG;
        {
          float t2 = ge * (0.f - vE);
          float t3 = gi * (-80.f - vE);
          float Itot = t2 + t3;
          float dv = 0.25f * ((-0.05f) * (vE - (-65.f)) + Itot);
          dv = dv * 0.0125f + dv * 0.9875f;      // _scale_grad forward (not fp-identity)
          vE = fmaxf(vE + dv, -200.f);
          rE = rE - 1; if (rE < 0) rE = 0;
          bool can = (rE == 0);
          bool sE = ((vE - (-50.f)) >= 0.f) && can;
          vE = (sE || !can) ? -65.f : vE;
          rE = sE ? 12 : rE;
          mE = __ballot(sE);
        }

        // ---- W0 prefetch for t+1 ----
        mInC = __ballot(n1 != 0.f);
        aRemC = 0ull;
        vaC[0] = vaC[1] = vaC[2] = vaC[3] = false;
        if (mInC) {
          unsigned long long a = mInC;
          int ja[4];
#pragma unroll
          for (int k = 0; k < 4; ++k) {
            vaC[k] = (a != 0ull); ja[k] = vaC[k] ? (__ffsll(a) - 1) : 0; a &= (a - 1ull);
          }
          aRemC = a;
#pragma unroll
          for (int k = 0; k < 4; ++k) fwC[k] = g_W0[ja[k] * N_E + tid];
        }

        cur = n1; n1 = n2;
      }
    } else {
      // ============ FALLBACK (wee != 0): old 4-wave barrier loop verbatim ============
      unsigned long long we0 = 0ull, we1 = 0ull, we2 = 0ull, we3 = 0ull;
      for (int t = 0; t < T; ++t) {
        const int slot = t & 1;
        const int tp = (t + 2 < T) ? (t + 2) : (T - 1);
        float n2 = g_in[(tp * BB + b) * N_IN + lane];

        float pEI = 0.f, kow = 0.f;
        {
          unsigned long long e = mE;
          while (e) {
            const float* qb[4];
#pragma unroll
            for (int k = 0; k < 4; ++k) {
              bool v = (e != 0ull); int j = v ? (__ffsll(e) - 1) : 0; e &= (e - 1ull);
              qb[k] = v ? &sWeiO[(base64 + j) * 80] : sZeroRow;
            }
            float fq[4], fr[4];
#pragma unroll
            for (int k = 0; k < 4; ++k) { fq[k] = qb[k][lane]; fr[k] = qb[k][colO]; }
#pragma unroll
            for (int k = 0; k < 4; ++k) pEI += fq[k];
#pragma unroll
            for (int k = 0; k < 4; ++k) kow += fr[k];
          }
        }
        sPK[slot][lane][wav] = pEI;
        if (lane < 16) sKoT[slot][lane][wav] = kow;
        asm volatile("s_waitcnt lgkmcnt(0)" ::: "memory");
        if (lane == 0) *((volatile unsigned*)&sTag[slot][wav]) = (unsigned)(t + 1);

        float kie = 0.f;
        {
          unsigned long long c = mI;
          while (c) {
            const float* pb[8];
#pragma unroll
            for (int k = 0; k < 8; ++k) {
              bool v = (c != 0ull); int j = v ? (__ffsll(c) - 1) : 0; c &= (c - 1ull);
              pb[k] = v ? &sWie[j * N_E] : sZeroRow;
            }
            float fI[8];
#pragma unroll
            for (int k = 0; k < 8; ++k) fI[k] = pb[k][tid];
#pragma unroll
            for (int k = 0; k < 8; ++k) kie += fI[k];
          }
        }

        float kin = 0.f;
        if (mInC) {
#pragma unroll
          for (int k = 0; k < 4; ++k) kin += vaC[k] ? fmaxf(fwC[k], 0.f) : 0.f;
          while (aRemC) {
            int j = __ffsll(aRemC) - 1; aRemC &= (aRemC - 1ull);
            kin += fmaxf(g_W0[j * N_E + tid], 0.f);
          }
        }

        float kee = 0.f;
        {
          unsigned long long m0 = we0, m1 = we1, m2 = we2, m3 = we3;
          while (m0 | m1 | m2 | m3) {
            int idx = 0;
            if (m0)      { idx = __ffsll(m0) - 1;       m0 &= (m0 - 1ull); }
            else if (m1) { idx = 64 + __ffsll(m1) - 1;  m1 &= (m1 - 1ull); }
            else if (m2) { idx = 128 + __ffsll(m2) - 1; m2 &= (m2 - 1ull); }
            else         { idx = 192 + __ffsll(m3) - 1; m3 &= (m3 - 1ull); }
            kee += g_Wee[idx * N_E + tid];
          }
        }

        ge = ((ge + kin) + kee) * dA;
        gi = (gi + kie) * dG;
        {
          float t2 = ge * (0.f - vE);
          float t3 = gi * (-80.f - vE);
          float Itot = t2 + t3;
          float dv = 0.25f * ((-0.05f) * (vE - (-65.f)) + Itot);
          dv = dv * 0.0125f + dv * 0.9875f;
          vE = fmaxf(vE + dv, -200.f);
          rE = rE - 1; if (rE < 0) rE = 0;
          bool can = (rE == 0);
          bool sE = ((vE - (-50.f)) >= 0.f) && can;
          vE = (sE || !can) ? -65.f : vE;
          rE = sE ? 12 : rE;
          unsigned long long fresh = __ballot(sE);
          if (lane == 0) sME[slot][wav] = fresh;
          mE = fresh;
        }

        mInC = __ballot(n1 != 0.f);
        aRemC = 0ull;
        vaC[0] = vaC[1] = vaC[2] = vaC[3] = false;
        if (mInC) {
          unsigned long long a = mInC;
          int ja[4];
#pragma unroll
          for (int k = 0; k < 4; ++k) {
            vaC[k] = (a != 0ull); ja[k] = vaC[k] ? (__ffsll(a) - 1) : 0; a &= (a - 1ull);
          }
          aRemC = a;
#pragma unroll
          for (int k = 0; k < 4; ++k) fwC[k] = g_W0[ja[k] * N_E + tid];
        }

        {
          const unsigned want = (unsigned)(t + 1);
          const unsigned long long want2 = (((unsigned long long)want) << 32) | want;
          volatile unsigned long long* vt = (volatile unsigned long long*)&sTag[slot][0];
          while (true) {
            unsigned long long a0 = vt[0], a1 = vt[1];
            if (((a0 ^ want2) | (a1 ^ want2)) == 0ull) break;
          }
          asm volatile("" ::: "memory");
        }

        float4 P = *(const float4*)&sPK[slot][lane][0];
        float4 K = *(const float4*)&sKoT[slot][col][0];

        {
          float p = ((P.x + P.y) + P.z) + P.w;
          gI = (gI + p) * dA;
          float Ii = gI * (0.f - vI);
          float dvi = 0.5f * ((-0.1f) * (vI - (-65.f)) + Ii);
          dvi = dvi * 0.0125f + dvi * 0.9875f;
          vI = fmaxf(vI + dvi, -200.f);
          rI = rI - 1; if (rI < 0) rI = 0;
          bool canI = (rI == 0);
          bool sI = ((vI - (-50.f)) >= 0.f) && canI;
          vI = (sI || !canI) ? -65.f : vI;
          rI = sI ? 6 : rI;
          mI = __ballot(sI);
        }

        {
          float ko = ((K.x + K.y) + K.z) + K.w;
          gO = (gO + ko) * dA;
          float Io = gO * (0.f - vO);
          float dvo = 0.25f * ((-0.05f) * (vO - (-65.f)) + Io);
          dvo = dvo * 0.0125f + dvo * 0.9875f;
          vO = fmaxf(vO + dvo, -200.f);
          rO = rO - 1; if (rO < 0) rO = 0;
          bool canO = (rO == 0);
          bool sO = ((vO - (-50.f)) >= 0.f) && canO;
          vO = (sO || !canO) ? -65.f : vO;
          rO = sO ? 12 : rO;
          accO += sO ? 1.f : 0.f;
        }

        __syncthreads();   // fallback path: make sME visible
        we0 = rfl64(sME[slot][0]); we1 = rfl64(sME[slot][1]);
        we2 = rfl64(sME[slot][2]); we3 = rfl64(sME[slot][3]);

        cur = n1; n1 = n2;
      }
    }
  } else {
    // ======================= WAVE 4: I/O CONSUMER =======================
    if (!wee) {
      for (int t = 0; t < T; ++t) {
        const int slot = t & 1;
        {
          const unsigned want = (unsigned)(t + 1);
          const unsigned long long want2 = (((unsigned long long)want) << 32) | want;
          volatile unsigned long long* vt = (volatile unsigned long long*)&sTag[slot][0];
          while (true) {
            unsigned long long a0 = vt[0], a1 = vt[1];
            if (((a0 ^ want2) | (a1 ^ want2)) == 0ull) break;
          }
          asm volatile("" ::: "memory");
        }
        float4 P = *(const float4*)&sPK[slot][lane][0];
        float4 K = *(const float4*)&sKoT[slot][col][0];

        // ---- I LIF -> ballot -> publish mI immediately (O-LIF after) ----
        {
          float p = ((P.x + P.y) + P.z) + P.w;
          gI = (gI + p) * dA;
          float Ii = gI * (0.f - vI);
          float dvi = 0.5f * ((-0.1f) * (vI - (-65.f)) + Ii);
          dvi = dvi * 0.0125f + dvi * 0.9875f;
          vI = fmaxf(vI + dvi, -200.f);
          rI = rI - 1; if (rI < 0) rI = 0;
          bool canI = (rI == 0);
          bool sI = ((vI - (-50.f)) >= 0.f) && canI;
          vI = (sI || !canI) ? -65.f : vI;
          rI = sI ? 6 : rI;
          unsigned long long mIv = __ballot(sI);
          if (lane == 0) {
            sMI[slot] = mIv;
            asm volatile("" ::: "memory");
            *((volatile unsigned*)&sMITag[slot]) = (unsigned)(t + 1);
          }
        }

        // ---- O LIF (off the recurrence critical path) ----
        {
          float ko = ((K.x + K.y) + K.z) + K.w;
          gO = (gO + ko) * dA;
          float Io = gO * (0.f - vO);
          float dvo = 0.25f * ((-0.05f) * (vO - (-65.f)) + Io);
          dvo = dvo * 0.0125f + dvo * 0.9875f;
          vO = fmaxf(vO + dvo, -200.f);
          rO = rO - 1; if (rO < 0) rO = 0;
          bool canO = (rO == 0);
          bool sO = ((vO - (-50.f)) >= 0.f) && canO;
          vO = (sO || !canO) ? -65.f : vO;
          rO = sO ? 12 : rO;
          accO += sO ? 1.f : 0.f;
        }
      }
    } else {
      for (int t = 0; t < T; ++t) __syncthreads();   // match fallback barrier count
    }
  }

  // ---- drain: O step T-1 over s_e(T-1) ----
  if (!wee) {
    float kd = 0.f;
    if (wav < 4) {
      unsigned long long e = mE;
      while (e) {
        const float* rb[8];
#pragma unroll
        for (int k = 0; k < 8; ++k) {
          bool v = (e != 0ull); int j = v ? (__ffsll(e) - 1) : 0; e &= (e - 1ull);
          rb[k] = v ? &sWeiO[(base64 + j) * 80] : sZeroRow;
        }
        float fr[8];
#pragma unroll
        for (int k = 0; k < 8; ++k) fr[k] = rb[k][colO];
#pragma unroll
        for (int k = 0; k < 8; ++k) kd += fr[k];
      }
    }
    __syncthreads();                 // wave4 done with all slots
    if (wav < 4 && lane < 16) sKoT[0][lane][wav] = kd;
    __syncthreads();
    if (wav == 4) {
      float4 K = *(const float4*)&sKoT[0][col][0];
      float ko = ((K.x + K.y) + K.z) + K.w;
      gO = (gO + ko) * dA;
      float Io = gO * (0.f - vO);
      float dvo = 0.25f * ((-0.05f) * (vO - (-65.f)) + Io);
      dvo = dvo * 0.0125f + dvo * 0.9875f;
      vO = fmaxf(vO + dvo, -200.f);
      rO = rO - 1; if (rO < 0) rO = 0;
      bool canO = (rO == 0);
      bool sO = ((vO - (-50.f)) >= 0.f) && canO;
      accO += sO ? 1.f : 0.f;
      if (lane < N_OUT) g_out[b * N_OUT + lane] = accO;
    }
  } else {
    float kd = 0.f;
    if (wav < 4) {
      unsigned long long e = mE;
      while (e) {
        const float* rb[4];
#pragma unroll
        for (int k = 0; k < 4; ++k) {
          bool v = (e != 0ull); int j = v ? (__ffsll(e) - 1) : 0; e &= (e - 1ull);
          rb[k] = v ? &sWeiO[(base64 + j) * 80] : sZeroRow;
        }
        float fr[4];
#pragma unroll
        for (int k = 0; k < 4; ++k) fr[k] = rb[k][colO];
#pragma unroll
        for (int k = 0; k < 4; ++k) kd += fr[k];
      }
    }
    __syncthreads();
    if (wav < 4 && lane < 16) sKoT[0][lane][wav] = kd;
    __syncthreads();
    if (wav < 4) {
      float4 K = *(const float4*)&sKoT[0][col][0];
      float ko = ((K.x + K.y) + K.z) + K.w;
      gO = (gO + ko) * dA;
      float Io = gO * (0.f - vO);
      float dvo = 0.25f * ((-0.05f) * (vO - (-65.f)) + Io);
      dvo = dvo * 0.0125f + dvo * 0.9875f;
      vO = fmaxf(vO + dvo, -200.f);
      rO = rO - 1; if (rO < 0) rO = 0;
      bool canO = (rO == 0);
      bool sO = ((vO - (-50.f)) >= 0.f) && canO;
      accO += sO ? 1.f : 0.f;
      if (wav == 0 && lane < N_OUT) g_out[b * N_OUT + lane] = accO;
    }
  }
}

extern "C" void kernel_launch(void* const* d_in, const int* in_sizes, int n_in,
                              void* d_out, int out_size, void* d_ws, size_t ws_size,
                              hipStream_t stream) {
  const float* g_in  = (const float*)d_in[0];
  const float* g_W0  = (const float*)d_in[1];
  const float* g_W1  = (const float*)d_in[2];
  const float* g_Wee = (const float*)d_in[3];
  const float* g_Wei = (const float*)d_in[4];
  const float* g_Wie = (const float*)d_in[5];
  float* out = (float*)d_out;
  int T = in_sizes[0] / (BB * N_IN);
  float dA = (float)exp(-0.25 / 2.0);   // tau_ampa = 2.0
  float dG = (float)exp(-0.25 / 9.0);   // tau_gaba = 9.0
  ping_kernel<<<dim3(BB), dim3(320), 0, stream>>>(g_in, g_W0, g_W1, g_Wee, g_Wei, g_Wie, out, T, dA, dG);
}

// Round 8
// 5237.045 us; speedup vs baseline: 1.0643x; 1.0643x over previous
//
#include <hip/hip_runtime.h>
#include <math.h>

#pragma clang fp contract(off)

#define BB 64      // batch
#define N_IN 64
#define N_E 256
#define N_I 64
#define N_OUT 10

__device__ inline unsigned long long rfl64(unsigned long long x) {
  unsigned int lo = __builtin_amdgcn_readfirstlane((unsigned int)x);
  unsigned int hi = __builtin_amdgcn_readfirstlane((unsigned int)(x >> 32));
  return (((unsigned long long)hi) << 32) | (unsigned long long)lo;
}

// r19 = r15 (verified 4762us bit-exact) with SOFTWARE-PIPELINED gathers.
// At the END of step t the producer:
//   (a) decodes mE(t) and issues the first-round E reads (fqP/frP) for t+1;
//   (b) resolves mI(t) (probe sMITag/sMI of slot t&1; poll on miss -- wave4
//       had nearly a full producer-step to respond) and issues the first-round
//       kie reads (fIP).
// Step t+1 then: sums the already-landed registers (no exposed LDS wait),
// publishes partials IMMEDIATELY (wave4 gets a full step of turnaround),
// finishes kie/W0/E-LIF, and runs the next tail. Decode work per step is
// IDENTICAL to r15 -- only moved (r18's mistake was duplicating decode).
// Remainder rounds (popc>8, rare) run in-step exactly as r15.
// Bit-exact: same reads, same zero-row pads (+0.0f on >=0 accumulators),
// same add order (first-8 round then remainder rounds), same publish->tag
// DS ordering, same LIF float sequences.
// Wave4 keeps r17's publish-early-mI (I-ballot before O-LIF).
__global__ __launch_bounds__(320, 1) void ping_kernel(
    const float* __restrict__ g_in,   // [T,64,64]
    const float* __restrict__ g_W0,   // [64,256]  clamp >=0 at use
    const float* __restrict__ g_W1,   // [256,10]  clamp >=0 at stage
    const float* __restrict__ g_Wee,  // [256,256]
    const float* __restrict__ g_Wei,  // [256,64]
    const float* __restrict__ g_Wie,  // [64,256]
    float* __restrict__ g_out,        // [64,10]
    int T, float dA, float dG)
{
  const int tid  = threadIdx.x;              // 0..319
  const int lane = tid & 63;
  const int wav  = tid >> 6;                 // 0..4
  const int b    = blockIdx.x;
  const int col  = (lane < N_OUT) ? lane : 0;
  const int colO = 64 + col;                 // W1 column inside merged row
  const int base64 = wav * 64;               // valid for wav<4

  __shared__ float sWie[N_I * N_E];          // 64 KB  [j][e]
  __shared__ float sWeiO[N_E * 80];          // 80 KB  [j][0:64)=Wei, [64:74)=W1
  __shared__ float sZeroRow[256];            // 1 KB zero row
  __shared__ __align__(16) float sPK[2][64][4];   // E->I partials [slot][lane][wave]
  __shared__ __align__(16) float sKoT[2][16][4];  // E->O partials [slot][col][wave]
  __shared__ __align__(16) unsigned sTag[2][4];   // partial tags (16B quads)
  __shared__ __align__(8) unsigned long long sMI[2];  // mI value per slot
  __shared__ unsigned sMITag[2];                      // mI tag per slot
  __shared__ unsigned long long sME[2][4];   // E masks (wee fallback only)
  __shared__ int sWee;

  // ---- one-time staging (320 threads) ----
  {
    const float4* s0 = (const float4*)g_Wie; float4* d0 = (float4*)sWie;
    for (int k = tid; k < (N_I * N_E) / 4; k += 320) d0[k] = s0[k];
    const float4* wei4 = (const float4*)g_Wei;         // [256][16] float4 view
    for (int k = tid; k < 256 * 16; k += 320) {
      int r = k >> 4, c4 = k & 15;
      *(float4*)&sWeiO[r * 80 + c4 * 4] = wei4[k];
    }
    for (int k = tid; k < 256 * N_OUT; k += 320) {
      int r = k / N_OUT, o = k - r * N_OUT;
      sWeiO[r * 80 + 64 + o] = fmaxf(g_W1[k], 0.f);
    }
    for (int k = tid; k < 256 * 6; k += 320) {
      int r = k / 6, c = k - r * 6;
      sWeiO[r * 80 + 74 + c] = 0.f;
    }
    for (int k = tid; k < 256; k += 320) sZeroRow[k] = 0.f;
  }
  if (tid < 8) sTag[tid >> 2][tid & 3] = 0u;
  if (tid < 8) sME[tid >> 2][tid & 3] = 0ull;
  if (tid < 2) { sMI[tid] = 0ull; sMITag[tid] = 0u; }
  if (tid == 0) sWee = 0;
  __syncthreads();
  // detect all-zero W_ee (true for this data; skipping a zero matmul is fp-exact)
  {
    bool any = false;
    const float4* p = (const float4*)g_Wee;
    for (int k = tid; k < (N_E * N_E) / 4; k += 320) {
      float4 x = p[k];
      any |= (x.x != 0.f) | (x.y != 0.f) | (x.z != 0.f) | (x.w != 0.f);
    }
    if (any) sWee = 1;   // benign race: all writers store 1
  }
  __syncthreads();
  const int wee = sWee;

  // ---- per-role state ----
  float vE = -65.f, ge = 0.f, gi = 0.f; int rE = 0;     // E neuron = tid (wav<4)
  unsigned long long mE = 0ull;                          // own E word, s_e(t-1)
  float vI = -65.f, gI = 0.f; int rI = 0;               // I neuron = lane
  unsigned long long mI = 0ull;                          // s_i(t-1) (fallback path)
  float vO = -65.f, gO = 0.f, accO = 0.f; int rO = 0;   // output (replicated)

  // input + W0 prefetch pipeline (producers only)
  float cur = 0.f, n1 = 0.f;
  unsigned long long mInC = 0ull, aRemC = 0ull;
  bool vaC[4] = {false, false, false, false};
  float fwC[4];
  if (wav < 4) {
    cur = g_in[b * N_IN + lane];
    n1  = g_in[((T > 1 ? 1 : 0) * BB + b) * N_IN + lane];
    mInC = __ballot(cur != 0.f);
    if (mInC) {
      unsigned long long a = mInC;
      int ja[4];
#pragma unroll
      for (int k = 0; k < 4; ++k) {
        vaC[k] = (a != 0ull); ja[k] = vaC[k] ? (__ffsll(a) - 1) : 0; a &= (a - 1ull);
      }
      aRemC = a;
#pragma unroll
      for (int k = 0; k < 4; ++k) fwC[k] = g_W0[ja[k] * N_E + tid];
    }
  }

  if (wav < 4) {
    if (!wee) {
      // ======= PRODUCER HOT LOOP (pipelined gathers; no exposed LDS wait) =======
      // pipeline state carried across iterations:
      float fqP[8], frP[8], fIP[8];            // pre-issued first-round reads
      unsigned long long mERem = 0ull;         // E mask beyond first 8 bits
      unsigned long long mKieRem = 0ull;       // kie mask beyond first 8 bits
      bool kieHave = false;                    // resolved mI != 0

      // init for t=0: mE = 0, mI(-1) = 0  (zero reads; sums to exact 0.0f)
#pragma unroll
      for (int k = 0; k < 8; ++k) { fqP[k] = sZeroRow[lane]; frP[k] = sZeroRow[colO]; }

      for (int t = 0; t < T; ++t) {
        const int slot = t & 1;

        const int tp = (t + 2 < T) ? (t + 2) : (T - 1);
        float n2 = g_in[(tp * BB + b) * N_IN + lane];   // prefetch t+2

        // ---- consume pre-issued E reads (first round) + rare remainder ----
        float pEI = 0.f, kow = 0.f;
#pragma unroll
        for (int k = 0; k < 8; ++k) pEI += fqP[k];
#pragma unroll
        for (int k = 0; k < 8; ++k) kow += frP[k];
        {
          unsigned long long e = mERem;
          while (e) {
            const float* qb[8];
#pragma unroll
            for (int k = 0; k < 8; ++k) {
              bool v = (e != 0ull); int j = v ? (__ffsll(e) - 1) : 0; e &= (e - 1ull);
              qb[k] = v ? &sWeiO[(base64 + j) * 80] : sZeroRow;
            }
            float fq[8], fr[8];
#pragma unroll
            for (int k = 0; k < 8; ++k) { fq[k] = qb[k][lane]; fr[k] = qb[k][colO]; }
#pragma unroll
            for (int k = 0; k < 8; ++k) pEI += fq[k];
#pragma unroll
            for (int k = 0; k < 8; ++k) kow += fr[k];
          }
        }

        // ---- publish partials, then tag (DS in-order; compiler barrier only) ----
        sPK[slot][lane][wav] = pEI;
        if (lane < 16) sKoT[slot][lane][wav] = kow;
        asm volatile("" ::: "memory");
        if (lane == 0) *((volatile unsigned*)&sTag[slot][wav]) = (unsigned)(t + 1);

        // ---- consume pre-issued kie reads (first round) + rare remainder ----
        float kie = 0.f;
        if (kieHave) {
#pragma unroll
          for (int k = 0; k < 8; ++k) kie += fIP[k];
          unsigned long long c = mKieRem;
          while (c) {
            const float* pb[8];
#pragma unroll
            for (int k = 0; k < 8; ++k) {
              bool v = (c != 0ull); int j = v ? (__ffsll(c) - 1) : 0; c &= (c - 1ull);
              pb[k] = v ? &sWie[j * N_E] : sZeroRow;
            }
            float fI[8];
#pragma unroll
            for (int k = 0; k < 8; ++k) fI[k] = pb[k][tid];
#pragma unroll
            for (int k = 0; k < 8; ++k) kie += fI[k];
          }
        }

        // ---- W0 consume (prefetched last iter; ascending) ----
        float kin = 0.f;
        if (mInC) {
#pragma unroll
          for (int k = 0; k < 4; ++k) kin += vaC[k] ? fmaxf(fwC[k], 0.f) : 0.f;
          while (aRemC) {
            int j = __ffsll(aRemC) - 1; aRemC &= (aRemC - 1ull);
            kin += fmaxf(g_W0[j * N_E + tid], 0.f);
          }
        }

        // ---- E LIF (COBA, C_m=1, g_L=0.05, ref=12) -> mE(t) ----
        ge = (ge + kin) * dA;           // kee == 0 exactly (wee false)
        gi = (gi + kie) * dG;
        {
          float t2 = ge * (0.f - vE);
          float t3 = gi * (-80.f - vE);
          float Itot = t2 + t3;
          float dv = 0.25f * ((-0.05f) * (vE - (-65.f)) + Itot);
          dv = dv * 0.0125f + dv * 0.9875f;      // _scale_grad forward (not fp-identity)
          vE = fmaxf(vE + dv, -200.f);
          rE = rE - 1; if (rE < 0) rE = 0;
          bool can = (rE == 0);
          bool sE = ((vE - (-50.f)) >= 0.f) && can;
          vE = (sE || !can) ? -65.f : vE;
          rE = sE ? 12 : rE;
          mE = __ballot(sE);
        }

        // ---- W0 prefetch for t+1 ----
        mInC = __ballot(n1 != 0.f);
        aRemC = 0ull;
        vaC[0] = vaC[1] = vaC[2] = vaC[3] = false;
        if (mInC) {
          unsigned long long a = mInC;
          int ja[4];
#pragma unroll
          for (int k = 0; k < 4; ++k) {
            vaC[k] = (a != 0ull); ja[k] = vaC[k] ? (__ffsll(a) - 1) : 0; a &= (a - 1ull);
          }
          aRemC = a;
#pragma unroll
          for (int k = 0; k < 4; ++k) fwC[k] = g_W0[ja[k] * N_E + tid];
        }

        // ---- TAIL (a): decode mE(t), issue first-round E reads for t+1 ----
        {
          unsigned long long e = mE;
#pragma unroll
          for (int k = 0; k < 8; ++k) {
            bool v = (e != 0ull); int j = v ? (__ffsll(e) - 1) : 0; e &= (e - 1ull);
            const float* q = v ? &sWeiO[(base64 + j) * 80] : sZeroRow;
            fqP[k] = q[lane]; frP[k] = q[colO];
          }
          mERem = e;
        }

        // ---- TAIL (b): resolve mI(t) (slot t&1, tag t+1); issue kie reads ----
        {
          unsigned tg = *((volatile unsigned*)&sMITag[slot]);
          unsigned long long md = *((volatile unsigned long long*)&sMI[slot]);
          unsigned long long mIc;
          if (tg == (unsigned)(t + 1)) {
            mIc = md;
          } else {
            volatile unsigned* vt = (volatile unsigned*)&sMITag[slot];
            while (*vt != (unsigned)(t + 1)) {}
            asm volatile("" ::: "memory");
            mIc = *((volatile unsigned long long*)&sMI[slot]);
          }
          kieHave = (mIc != 0ull);
          unsigned long long c = mIc;
#pragma unroll
          for (int k = 0; k < 8; ++k) {
            bool v = (c != 0ull); int j = v ? (__ffsll(c) - 1) : 0; c &= (c - 1ull);
            const float* p = v ? &sWie[j * N_E] : sZeroRow;
            fIP[k] = p[tid];
          }
          mKieRem = c;
        }

        cur = n1; n1 = n2;
      }
    } else {
      // ============ FALLBACK (wee != 0): old 4-wave barrier loop verbatim ============
      unsigned long long we0 = 0ull, we1 = 0ull, we2 = 0ull, we3 = 0ull;
      for (int t = 0; t < T; ++t) {
        const int slot = t & 1;
        const int tp = (t + 2 < T) ? (t + 2) : (T - 1);
        float n2 = g_in[(tp * BB + b) * N_IN + lane];

        float pEI = 0.f, kow = 0.f;
        {
          unsigned long long e = mE;
          while (e) {
            const float* qb[4];
#pragma unroll
            for (int k = 0; k < 4; ++k) {
              bool v = (e != 0ull); int j = v ? (__ffsll(e) - 1) : 0; e &= (e - 1ull);
              qb[k] = v ? &sWeiO[(base64 + j) * 80] : sZeroRow;
            }
            float fq[4], fr[4];
#pragma unroll
            for (int k = 0; k < 4; ++k) { fq[k] = qb[k][lane]; fr[k] = qb[k][colO]; }
#pragma unroll
            for (int k = 0; k < 4; ++k) pEI += fq[k];
#pragma unroll
            for (int k = 0; k < 4; ++k) kow += fr[k];
          }
        }
        sPK[slot][lane][wav] = pEI;
        if (lane < 16) sKoT[slot][lane][wav] = kow;
        asm volatile("s_waitcnt lgkmcnt(0)" ::: "memory");
        if (lane == 0) *((volatile unsigned*)&sTag[slot][wav]) = (unsigned)(t + 1);

        float kie = 0.f;
        {
          unsigned long long c = mI;
          while (c) {
            const float* pb[8];
#pragma unroll
            for (int k = 0; k < 8; ++k) {
              bool v = (c != 0ull); int j = v ? (__ffsll(c) - 1) : 0; c &= (c - 1ull);
              pb[k] = v ? &sWie[j * N_E] : sZeroRow;
            }
            float fI[8];
#pragma unroll
            for (int k = 0; k < 8; ++k) fI[k] = pb[k][tid];
#pragma unroll
            for (int k = 0; k < 8; ++k) kie += fI[k];
          }
        }

        float kin = 0.f;
        if (mInC) {
#pragma unroll
          for (int k = 0; k < 4; ++k) kin += vaC[k] ? fmaxf(fwC[k], 0.f) : 0.f;
          while (aRemC) {
            int j = __ffsll(aRemC) - 1; aRemC &= (aRemC - 1ull);
            kin += fmaxf(g_W0[j * N_E + tid], 0.f);
          }
        }

        float kee = 0.f;
        {
          unsigned long long m0 = we0, m1 = we1, m2 = we2, m3 = we3;
          while (m0 | m1 | m2 | m3) {
            int idx = 0;
            if (m0)      { idx = __ffsll(m0) - 1;       m0 &= (m0 - 1ull); }
            else if (m1) { idx = 64 + __ffsll(m1) - 1;  m1 &= (m1 - 1ull); }
            else if (m2) { idx = 128 + __ffsll(m2) - 1; m2 &= (m2 - 1ull); }
            else         { idx = 192 + __ffsll(m3) - 1; m3 &= (m3 - 1ull); }
            kee += g_Wee[idx * N_E + tid];
          }
        }

        ge = ((ge + kin) + kee) * dA;
        gi = (gi + kie) * dG;
        {
          float t2 = ge * (0.f - vE);
          float t3 = gi * (-80.f - vE);
          float Itot = t2 + t3;
          float dv = 0.25f * ((-0.05f) * (vE - (-65.f)) + Itot);
          dv = dv * 0.0125f + dv * 0.9875f;
          vE = fmaxf(vE + dv, -200.f);
          rE = rE - 1; if (rE < 0) rE = 0;
          bool can = (rE == 0);
          bool sE = ((vE - (-50.f)) >= 0.f) && can;
          vE = (sE || !can) ? -65.f : vE;
          rE = sE ? 12 : rE;
          unsigned long long fresh = __ballot(sE);
          if (lane == 0) sME[slot][wav] = fresh;
          mE = fresh;
        }

        mInC = __ballot(n1 != 0.f);
        aRemC = 0ull;
        vaC[0] = vaC[1] = vaC[2] = vaC[3] = false;
        if (mInC) {
          unsigned long long a = mInC;
          int ja[4];
#pragma unroll
          for (int k = 0; k < 4; ++k) {
            vaC[k] = (a != 0ull); ja[k] = vaC[k] ? (__ffsll(a) - 1) : 0; a &= (a - 1ull);
          }
          aRemC = a;
#pragma unroll
          for (int k = 0; k < 4; ++k) fwC[k] = g_W0[ja[k] * N_E + tid];
        }

        {
          const unsigned want = (unsigned)(t + 1);
          const unsigned long long want2 = (((unsigned long long)want) << 32) | want;
          volatile unsigned long long* vt = (volatile unsigned long long*)&sTag[slot][0];
          while (true) {
            unsigned long long a0 = vt[0], a1 = vt[1];
            if (((a0 ^ want2) | (a1 ^ want2)) == 0ull) break;
          }
          asm volatile("" ::: "memory");
        }

        float4 P = *(const float4*)&sPK[slot][lane][0];
        float4 K = *(const float4*)&sKoT[slot][col][0];

        {
          float p = ((P.x + P.y) + P.z) + P.w;
          gI = (gI + p) * dA;
          float Ii = gI * (0.f - vI);
          float dvi = 0.5f * ((-0.1f) * (vI - (-65.f)) + Ii);
          dvi = dvi * 0.0125f + dvi * 0.9875f;
          vI = fmaxf(vI + dvi, -200.f);
          rI = rI - 1; if (rI < 0) rI = 0;
          bool canI = (rI == 0);
          bool sI = ((vI - (-50.f)) >= 0.f) && canI;
          vI = (sI || !canI) ? -65.f : vI;
          rI = sI ? 6 : rI;
          mI = __ballot(sI);
        }

        {
          float ko = ((K.x + K.y) + K.z) + K.w;
          gO = (gO + ko) * dA;
          float Io = gO * (0.f - vO);
          float dvo = 0.25f * ((-0.05f) * (vO - (-65.f)) + Io);
          dvo = dvo * 0.0125f + dvo * 0.9875f;
          vO = fmaxf(vO + dvo, -200.f);
          rO = rO - 1; if (rO < 0) rO = 0;
          bool canO = (rO == 0);
          bool sO = ((vO - (-50.f)) >= 0.f) && canO;
          vO = (sO || !canO) ? -65.f : vO;
          rO = sO ? 12 : rO;
          accO += sO ? 1.f : 0.f;
        }

        __syncthreads();   // fallback path: make sME visible
        we0 = rfl64(sME[slot][0]); we1 = rfl64(sME[slot][1]);
        we2 = rfl64(sME[slot][2]); we3 = rfl64(sME[slot][3]);

        cur = n1; n1 = n2;
      }
    }
  } else {
    // ======================= WAVE 4: I/O CONSUMER =======================
    if (!wee) {
      for (int t = 0; t < T; ++t) {
        const int slot = t & 1;
        {
          const unsigned want = (unsigned)(t + 1);
          const unsigned long long want2 = (((unsigned long long)want) << 32) | want;
          volatile unsigned long long* vt = (volatile unsigned long long*)&sTag[slot][0];
          while (true) {
            unsigned long long a0 = vt[0], a1 = vt[1];
            if (((a0 ^ want2) | (a1 ^ want2)) == 0ull) break;
          }
          asm volatile("" ::: "memory");
        }
        float4 P = *(const float4*)&sPK[slot][lane][0];
        float4 K = *(const float4*)&sKoT[slot][col][0];

        // ---- I LIF -> ballot -> publish mI immediately (O-LIF after) ----
        {
          float p = ((P.x + P.y) + P.z) + P.w;
          gI = (gI + p) * dA;
          float Ii = gI * (0.f - vI);
          float dvi = 0.5f * ((-0.1f) * (vI - (-65.f)) + Ii);
          dvi = dvi * 0.0125f + dvi * 0.9875f;
          vI = fmaxf(vI + dvi, -200.f);
          rI = rI - 1; if (rI < 0) rI = 0;
          bool canI = (rI == 0);
          bool sI = ((vI - (-50.f)) >= 0.f) && canI;
          vI = (sI || !canI) ? -65.f : vI;
          rI = sI ? 6 : rI;
          unsigned long long mIv = __ballot(sI);
          if (lane == 0) {
            sMI[slot] = mIv;
            asm volatile("" ::: "memory");
            *((volatile unsigned*)&sMITag[slot]) = (unsigned)(t + 1);
          }
        }

        // ---- O LIF (off the recurrence critical path) ----
        {
          float ko = ((K.x + K.y) + K.z) + K.w;
          gO = (gO + ko) * dA;
          float Io = gO * (0.f - vO);
          float dvo = 0.25f * ((-0.05f) * (vO - (-65.f)) + Io);
          dvo = dvo * 0.0125f + dvo * 0.9875f;
          vO = fmaxf(vO + dvo, -200.f);
          rO = rO - 1; if (rO < 0) rO = 0;
          bool canO = (rO == 0);
          bool sO = ((vO - (-50.f)) >= 0.f) && canO;
          vO = (sO || !canO) ? -65.f : vO;
          rO = sO ? 12 : rO;
          accO += sO ? 1.f : 0.f;
        }
      }
    } else {
      for (int t = 0; t < T; ++t) __syncthreads();   // match fallback barrier count
    }
  }

  // ---- drain: O step T-1 over s_e(T-1) ----
  if (!wee) {
    float kd = 0.f;
    if (wav < 4) {
      unsigned long long e = mE;
      while (e) {
        const float* rb[8];
#pragma unroll
        for (int k = 0; k < 8; ++k) {
          bool v = (e != 0ull); int j = v ? (__ffsll(e) - 1) : 0; e &= (e - 1ull);
          rb[k] = v ? &sWeiO[(base64 + j) * 80] : sZeroRow;
        }
        float fr[8];
#pragma unroll
        for (int k = 0; k < 8; ++k) fr[k] = rb[k][colO];
#pragma unroll
        for (int k = 0; k < 8; ++k) kd += fr[k];
      }
    }
    __syncthreads();                 // wave4 done with all slots
    if (wav < 4 && lane < 16) sKoT[0][lane][wav] = kd;
    __syncthreads();
    if (wav == 4) {
      float4 K = *(const float4*)&sKoT[0][col][0];
      float ko = ((K.x + K.y) + K.z) + K.w;
      gO = (gO + ko) * dA;
      float Io = gO * (0.f - vO);
      float dvo = 0.25f * ((-0.05f) * (vO - (-65.f)) + Io);
      dvo = dvo * 0.0125f + dvo * 0.9875f;
      vO = fmaxf(vO + dvo, -200.f);
      rO = rO - 1; if (rO < 0) rO = 0;
      bool canO = (rO == 0);
      bool sO = ((vO - (-50.f)) >= 0.f) && canO;
      accO += sO ? 1.f : 0.f;
      if (lane < N_OUT) g_out[b * N_OUT + lane] = accO;
    }
  } else {
    float kd = 0.f;
    if (wav < 4) {
      unsigned long long e = mE;
      while (e) {
        const float* rb[4];
#pragma unroll
        for (int k = 0; k < 4; ++k) {
          bool v = (e != 0ull); int j = v ? (__ffsll(e) - 1) : 0; e &= (e - 1ull);
          rb[k] = v ? &sWeiO[(base64 + j) * 80] : sZeroRow;
        }
        float fr[4];
#pragma unroll
        for (int k = 0; k < 4; ++k) fr[k] = rb[k][colO];
#pragma unroll
        for (int k = 0; k < 4; ++k) kd += fr[k];
      }
    }
    __syncthreads();
    if (wav < 4 && lane < 16) sKoT[0][lane][wav] = kd;
    __syncthreads();
    if (wav < 4) {
      float4 K = *(const float4*)&sKoT[0][col][0];
      float ko = ((K.x + K.y) + K.z) + K.w;
      gO = (gO + ko) * dA;
      float Io = gO * (0.f - vO);
      float dvo = 0.25f * ((-0.05f) * (vO - (-65.f)) + Io);
      dvo = dvo * 0.0125f + dvo * 0.9875f;
      vO = fmaxf(vO + dvo, -200.f);
      rO = rO - 1; if (rO < 0) rO = 0;
      bool canO = (rO == 0);
      bool sO = ((vO - (-50.f)) >= 0.f) && canO;
      accO += sO ? 1.f : 0.f;
      if (wav == 0 && lane < N_OUT) g_out[b * N_OUT + lane] = accO;
    }
  }
}

extern "C" void kernel_launch(void* const* d_in, const int* in_sizes, int n_in,
                              void* d_out, int out_size, void* d_ws, size_t ws_size,
                              hipStream_t stream) {
  const float* g_in  = (const float*)d_in[0];
  const float* g_W0  = (const float*)d_in[1];
  const float* g_W1  = (const float*)d_in[2];
  const float* g_Wee = (const float*)d_in[3];
  const float* g_Wei = (const float*)d_in[4];
  const float* g_Wie = (const float*)d_in[5];
  float* out = (float*)d_out;
  int T = in_sizes[0] / (BB * N_IN);
  float dA = (float)exp(-0.25 / 2.0);   // tau_ampa = 2.0
  float dG = (float)exp(-0.25 / 9.0);   // tau_gaba = 9.0
  ping_kernel<<<dim3(BB), dim3(320), 0, stream>>>(g_in, g_W0, g_W1, g_Wee, g_Wei, g_Wie, out, T, dA, dG);
}

// Round 9
// 4727.859 us; speedup vs baseline: 1.1789x; 1.1077x over previous
//
#include <hip/hip_runtime.h>
#include <math.h>

#pragma clang fp contract(off)

#define BB 64      // batch
#define N_IN 64
#define N_E 256
#define N_I 64
#define N_OUT 10

__device__ inline unsigned long long rfl64(unsigned long long x) {
  unsigned int lo = __builtin_amdgcn_readfirstlane((unsigned int)x);
  unsigned int hi = __builtin_amdgcn_readfirstlane((unsigned int)(x >> 32));
  return (((unsigned long long)hi) << 32) | (unsigned long long)lo;
}

// r20 = r15 RESTORED VERBATIM (verified 4762us, bit-exact, Round 3).
// Rationale: r16 (dense), r17 (publish-early+kie16), r18 (spec merge), r19
// (sw pipeline) all regressed 5-17%; r13 (lockstep) == r15 (handoff) ==
// ~4765us across distinct sync architectures. The floor is the serial
// recurrence's latency chain with a near-minimal instruction stream; every
// added instruction costs its issue time and no stall is recoverable.
// This restores the best-known kernel as the session's final state.
//
// Structure: waves 0-3 producers (E-side, own 64-bit word of s_e), wave 4
// consumer (I/O-side). Producers' steady-state hot path has NO polls/barriers:
// partials publish via data->compiler-barrier->tag (DS in-order), mI(t-1)
// resolved by early tag+data probe with poll fallback. All float sequences /
// gather orders / reduction associations bit-identical to the verified 4770us
// lockstep kernel (batch-8 zero-row padding adds exact +0.0f).
__global__ __launch_bounds__(320, 1) void ping_kernel(
    const float* __restrict__ g_in,   // [T,64,64]
    const float* __restrict__ g_W0,   // [64,256]  clamp >=0 at use
    const float* __restrict__ g_W1,   // [256,10]  clamp >=0 at stage
    const float* __restrict__ g_Wee,  // [256,256]
    const float* __restrict__ g_Wei,  // [256,64]
    const float* __restrict__ g_Wie,  // [64,256]
    float* __restrict__ g_out,        // [64,10]
    int T, float dA, float dG)
{
  const int tid  = threadIdx.x;              // 0..319
  const int lane = tid & 63;
  const int wav  = tid >> 6;                 // 0..4
  const int b    = blockIdx.x;
  const int col  = (lane < N_OUT) ? lane : 0;
  const int colO = 64 + col;                 // W1 column inside merged row
  const int base64 = wav * 64;               // valid for wav<4

  __shared__ float sWie[N_I * N_E];          // 64 KB  [j][e]
  __shared__ float sWeiO[N_E * 80];          // 80 KB  [j][0:64)=Wei, [64:74)=W1
  __shared__ float sZeroRow[256];            // 1 KB zero row
  __shared__ __align__(16) float sPK[2][64][4];   // E->I partials [slot][lane][wave]
  __shared__ __align__(16) float sKoT[2][16][4];  // E->O partials [slot][col][wave]
  __shared__ __align__(16) unsigned sTag[2][4];   // partial tags (16B quads)
  __shared__ __align__(8) unsigned long long sMI[2];  // mI value per slot
  __shared__ unsigned sMITag[2];                      // mI tag per slot
  __shared__ unsigned long long sME[2][4];   // E masks (wee fallback only)
  __shared__ int sWee;

  // ---- one-time staging (320 threads) ----
  {
    const float4* s0 = (const float4*)g_Wie; float4* d0 = (float4*)sWie;
    for (int k = tid; k < (N_I * N_E) / 4; k += 320) d0[k] = s0[k];
    const float4* wei4 = (const float4*)g_Wei;         // [256][16] float4 view
    for (int k = tid; k < 256 * 16; k += 320) {
      int r = k >> 4, c4 = k & 15;
      *(float4*)&sWeiO[r * 80 + c4 * 4] = wei4[k];
    }
    for (int k = tid; k < 256 * N_OUT; k += 320) {
      int r = k / N_OUT, o = k - r * N_OUT;
      sWeiO[r * 80 + 64 + o] = fmaxf(g_W1[k], 0.f);
    }
    for (int k = tid; k < 256 * 6; k += 320) {
      int r = k / 6, c = k - r * 6;
      sWeiO[r * 80 + 74 + c] = 0.f;
    }
    for (int k = tid; k < 256; k += 320) sZeroRow[k] = 0.f;
  }
  if (tid < 8) sTag[tid >> 2][tid & 3] = 0u;
  if (tid < 8) sME[tid >> 2][tid & 3] = 0ull;
  if (tid < 2) { sMI[tid] = 0ull; sMITag[tid] = 0u; }
  if (tid == 0) sWee = 0;
  __syncthreads();
  // detect all-zero W_ee (true for this data; skipping a zero matmul is fp-exact)
  {
    bool any = false;
    const float4* p = (const float4*)g_Wee;
    for (int k = tid; k < (N_E * N_E) / 4; k += 320) {
      float4 x = p[k];
      any |= (x.x != 0.f) | (x.y != 0.f) | (x.z != 0.f) | (x.w != 0.f);
    }
    if (any) sWee = 1;   // benign race: all writers store 1
  }
  __syncthreads();
  const int wee = sWee;

  // ---- per-role state ----
  float vE = -65.f, ge = 0.f, gi = 0.f; int rE = 0;     // E neuron = tid (wav<4)
  unsigned long long mE = 0ull;                          // own E word, s_e(t-1)
  float vI = -65.f, gI = 0.f; int rI = 0;               // I neuron = lane
  unsigned long long mI = 0ull;                          // s_i(t-1)
  float vO = -65.f, gO = 0.f, accO = 0.f; int rO = 0;   // output (replicated)

  // input + W0 prefetch pipeline (producers only)
  float cur = 0.f, n1 = 0.f;
  unsigned long long mInC = 0ull, aRemC = 0ull;
  bool vaC[4] = {false, false, false, false};
  float fwC[4];
  if (wav < 4) {
    cur = g_in[b * N_IN + lane];
    n1  = g_in[((T > 1 ? 1 : 0) * BB + b) * N_IN + lane];
    mInC = __ballot(cur != 0.f);
    if (mInC) {
      unsigned long long a = mInC;
      int ja[4];
#pragma unroll
      for (int k = 0; k < 4; ++k) {
        vaC[k] = (a != 0ull); ja[k] = vaC[k] ? (__ffsll(a) - 1) : 0; a &= (a - 1ull);
      }
      aRemC = a;
#pragma unroll
      for (int k = 0; k < 4; ++k) fwC[k] = g_W0[ja[k] * N_E + tid];
    }
  }

  if (wav < 4) {
    if (!wee) {
      // ================= PRODUCER HOT LOOP (no polls in steady state) =================
      for (int t = 0; t < T; ++t) {
        const int slot = t & 1;
        const int slotP = (t + 1) & 1;       // slot holding mI(t-1)
        // early probe for mI(t-1): tag THEN data (both volatile, in-order DS)
        unsigned tgP = *((volatile unsigned*)&sMITag[slotP]);
        unsigned long long mdP = *((volatile unsigned long long*)&sMI[slotP]);

        const int tp = (t + 2 < T) ? (t + 2) : (T - 1);
        float n2 = g_in[(tp * BB + b) * N_IN + lane];   // prefetch t+2

        // ---- E gather over own word of s_e(t-1): pEI/kow, ascending, batch 8 ----
        float pEI = 0.f, kow = 0.f;
        {
          unsigned long long e = mE;
          while (e) {
            const float* qb[8];
#pragma unroll
            for (int k = 0; k < 8; ++k) {
              bool v = (e != 0ull); int j = v ? (__ffsll(e) - 1) : 0; e &= (e - 1ull);
              qb[k] = v ? &sWeiO[(base64 + j) * 80] : sZeroRow;
            }
            float fq[8], fr[8];
#pragma unroll
            for (int k = 0; k < 8; ++k) { fq[k] = qb[k][lane]; fr[k] = qb[k][colO]; }
#pragma unroll
            for (int k = 0; k < 8; ++k) pEI += fq[k];
#pragma unroll
            for (int k = 0; k < 8; ++k) kow += fr[k];
          }
        }

        // ---- publish partials, then tag (DS in-order; compiler barrier only) ----
        sPK[slot][lane][wav] = pEI;
        if (lane < 16) sKoT[slot][lane][wav] = kow;
        asm volatile("" ::: "memory");
        if (lane == 0) *((volatile unsigned*)&sTag[slot][wav]) = (unsigned)(t + 1);

        // ---- resolve mI(t-1): probe hit expected (wave4 has ~1 step slack) ----
        unsigned long long mIc;
        if (tgP == (unsigned)t) {
          mIc = mdP;
        } else {
          volatile unsigned* vt = (volatile unsigned*)&sMITag[slotP];
          while (*vt != (unsigned)t) {}
          asm volatile("" ::: "memory");
          mIc = *((volatile unsigned long long*)&sMI[slotP]);
        }

        // ---- kie gather over mI(t-1) ----
        float kie = 0.f;
        {
          unsigned long long c = mIc;
          while (c) {
            const float* pb[8];
#pragma unroll
            for (int k = 0; k < 8; ++k) {
              bool v = (c != 0ull); int j = v ? (__ffsll(c) - 1) : 0; c &= (c - 1ull);
              pb[k] = v ? &sWie[j * N_E] : sZeroRow;
            }
            float fI[8];
#pragma unroll
            for (int k = 0; k < 8; ++k) fI[k] = pb[k][tid];
#pragma unroll
            for (int k = 0; k < 8; ++k) kie += fI[k];
          }
        }

        // ---- W0 consume (prefetched last iter; ascending) ----
        float kin = 0.f;
        if (mInC) {
#pragma unroll
          for (int k = 0; k < 4; ++k) kin += vaC[k] ? fmaxf(fwC[k], 0.f) : 0.f;
          while (aRemC) {
            int j = __ffsll(aRemC) - 1; aRemC &= (aRemC - 1ull);
            kin += fmaxf(g_W0[j * N_E + tid], 0.f);
          }
        }

        // ---- E LIF (COBA, C_m=1, g_L=0.05, ref=12) -> mE(t) ----
        ge = (ge + kin) * dA;           // kee == 0 exactly (wee false)
        gi = (gi + kie) * dG;
        {
          float t2 = ge * (0.f - vE);
          float t3 = gi * (-80.f - vE);
          float Itot = t2 + t3;
          float dv = 0.25f * ((-0.05f) * (vE - (-65.f)) + Itot);
          dv = dv * 0.0125f + dv * 0.9875f;      // _scale_grad forward (not fp-identity)
          vE = fmaxf(vE + dv, -200.f);
          rE = rE - 1; if (rE < 0) rE = 0;
          bool can = (rE == 0);
          bool sE = ((vE - (-50.f)) >= 0.f) && can;
          vE = (sE || !can) ? -65.f : vE;
          rE = sE ? 12 : rE;
          mE = __ballot(sE);
        }

        // ---- W0 prefetch for t+1 ----
        mInC = __ballot(n1 != 0.f);
        aRemC = 0ull;
        vaC[0] = vaC[1] = vaC[2] = vaC[3] = false;
        if (mInC) {
          unsigned long long a = mInC;
          int ja[4];
#pragma unroll
          for (int k = 0; k < 4; ++k) {
            vaC[k] = (a != 0ull); ja[k] = vaC[k] ? (__ffsll(a) - 1) : 0; a &= (a - 1ull);
          }
          aRemC = a;
#pragma unroll
          for (int k = 0; k < 4; ++k) fwC[k] = g_W0[ja[k] * N_E + tid];
        }

        cur = n1; n1 = n2;
      }
    } else {
      // ============ FALLBACK (wee != 0): old 4-wave barrier loop verbatim ============
      unsigned long long we0 = 0ull, we1 = 0ull, we2 = 0ull, we3 = 0ull;
      for (int t = 0; t < T; ++t) {
        const int slot = t & 1;
        const int tp = (t + 2 < T) ? (t + 2) : (T - 1);
        float n2 = g_in[(tp * BB + b) * N_IN + lane];

        float pEI = 0.f, kow = 0.f;
        {
          unsigned long long e = mE;
          while (e) {
            const float* qb[4];
#pragma unroll
            for (int k = 0; k < 4; ++k) {
              bool v = (e != 0ull); int j = v ? (__ffsll(e) - 1) : 0; e &= (e - 1ull);
              qb[k] = v ? &sWeiO[(base64 + j) * 80] : sZeroRow;
            }
            float fq[4], fr[4];
#pragma unroll
            for (int k = 0; k < 4; ++k) { fq[k] = qb[k][lane]; fr[k] = qb[k][colO]; }
#pragma unroll
            for (int k = 0; k < 4; ++k) pEI += fq[k];
#pragma unroll
            for (int k = 0; k < 4; ++k) kow += fr[k];
          }
        }
        sPK[slot][lane][wav] = pEI;
        if (lane < 16) sKoT[slot][lane][wav] = kow;
        asm volatile("s_waitcnt lgkmcnt(0)" ::: "memory");
        if (lane == 0) *((volatile unsigned*)&sTag[slot][wav]) = (unsigned)(t + 1);

        float kie = 0.f;
        {
          unsigned long long c = mI;
          while (c) {
            const float* pb[8];
#pragma unroll
            for (int k = 0; k < 8; ++k) {
              bool v = (c != 0ull); int j = v ? (__ffsll(c) - 1) : 0; c &= (c - 1ull);
              pb[k] = v ? &sWie[j * N_E] : sZeroRow;
            }
            float fI[8];
#pragma unroll
            for (int k = 0; k < 8; ++k) fI[k] = pb[k][tid];
#pragma unroll
            for (int k = 0; k < 8; ++k) kie += fI[k];
          }
        }

        float kin = 0.f;
        if (mInC) {
#pragma unroll
          for (int k = 0; k < 4; ++k) kin += vaC[k] ? fmaxf(fwC[k], 0.f) : 0.f;
          while (aRemC) {
            int j = __ffsll(aRemC) - 1; aRemC &= (aRemC - 1ull);
            kin += fmaxf(g_W0[j * N_E + tid], 0.f);
          }
        }

        float kee = 0.f;
        {
          unsigned long long m0 = we0, m1 = we1, m2 = we2, m3 = we3;
          while (m0 | m1 | m2 | m3) {
            int idx = 0;
            if (m0)      { idx = __ffsll(m0) - 1;       m0 &= (m0 - 1ull); }
            else if (m1) { idx = 64 + __ffsll(m1) - 1;  m1 &= (m1 - 1ull); }
            else if (m2) { idx = 128 + __ffsll(m2) - 1; m2 &= (m2 - 1ull); }
            else         { idx = 192 + __ffsll(m3) - 1; m3 &= (m3 - 1ull); }
            kee += g_Wee[idx * N_E + tid];
          }
        }

        ge = ((ge + kin) + kee) * dA;
        gi = (gi + kie) * dG;
        {
          float t2 = ge * (0.f - vE);
          float t3 = gi * (-80.f - vE);
          float Itot = t2 + t3;
          float dv = 0.25f * ((-0.05f) * (vE - (-65.f)) + Itot);
          dv = dv * 0.0125f + dv * 0.9875f;
          vE = fmaxf(vE + dv, -200.f);
          rE = rE - 1; if (rE < 0) rE = 0;
          bool can = (rE == 0);
          bool sE = ((vE - (-50.f)) >= 0.f) && can;
          vE = (sE || !can) ? -65.f : vE;
          rE = sE ? 12 : rE;
          unsigned long long fresh = __ballot(sE);
          if (lane == 0) sME[slot][wav] = fresh;
          mE = fresh;
        }

        mInC = __ballot(n1 != 0.f);
        aRemC = 0ull;
        vaC[0] = vaC[1] = vaC[2] = vaC[3] = false;
        if (mInC) {
          unsigned long long a = mInC;
          int ja[4];
#pragma unroll
          for (int k = 0; k < 4; ++k) {
            vaC[k] = (a != 0ull); ja[k] = vaC[k] ? (__ffsll(a) - 1) : 0; a &= (a - 1ull);
          }
          aRemC = a;
#pragma unroll
          for (int k = 0; k < 4; ++k) fwC[k] = g_W0[ja[k] * N_E + tid];
        }

        {
          const unsigned want = (unsigned)(t + 1);
          const unsigned long long want2 = (((unsigned long long)want) << 32) | want;
          volatile unsigned long long* vt = (volatile unsigned long long*)&sTag[slot][0];
          while (true) {
            unsigned long long a0 = vt[0], a1 = vt[1];
            if (((a0 ^ want2) | (a1 ^ want2)) == 0ull) break;
          }
          asm volatile("" ::: "memory");
        }

        float4 P = *(const float4*)&sPK[slot][lane][0];
        float4 K = *(const float4*)&sKoT[slot][col][0];

        {
          float p = ((P.x + P.y) + P.z) + P.w;
          gI = (gI + p) * dA;
          float Ii = gI * (0.f - vI);
          float dvi = 0.5f * ((-0.1f) * (vI - (-65.f)) + Ii);
          dvi = dvi * 0.0125f + dvi * 0.9875f;
          vI = fmaxf(vI + dvi, -200.f);
          rI = rI - 1; if (rI < 0) rI = 0;
          bool canI = (rI == 0);
          bool sI = ((vI - (-50.f)) >= 0.f) && canI;
          vI = (sI || !canI) ? -65.f : vI;
          rI = sI ? 6 : rI;
          mI = __ballot(sI);
        }

        {
          float ko = ((K.x + K.y) + K.z) + K.w;
          gO = (gO + ko) * dA;
          float Io = gO * (0.f - vO);
          float dvo = 0.25f * ((-0.05f) * (vO - (-65.f)) + Io);
          dvo = dvo * 0.0125f + dvo * 0.9875f;
          vO = fmaxf(vO + dvo, -200.f);
          rO = rO - 1; if (rO < 0) rO = 0;
          bool canO = (rO == 0);
          bool sO = ((vO - (-50.f)) >= 0.f) && canO;
          vO = (sO || !canO) ? -65.f : vO;
          rO = sO ? 12 : rO;
          accO += sO ? 1.f : 0.f;
        }

        __syncthreads();   // fallback path: make sME visible
        we0 = rfl64(sME[slot][0]); we1 = rfl64(sME[slot][1]);
        we2 = rfl64(sME[slot][2]); we3 = rfl64(sME[slot][3]);

        cur = n1; n1 = n2;
      }
    }
  } else {
    // ======================= WAVE 4: I/O CONSUMER =======================
    if (!wee) {
      for (int t = 0; t < T; ++t) {
        const int slot = t & 1;
        // poll the 4 partial tags (slack absorbs producer skew)
        {
          const unsigned want = (unsigned)(t + 1);
          const unsigned long long want2 = (((unsigned long long)want) << 32) | want;
          volatile unsigned long long* vt = (volatile unsigned long long*)&sTag[slot][0];
          while (true) {
            unsigned long long a0 = vt[0], a1 = vt[1];
            if (((a0 ^ want2) | (a1 ^ want2)) == 0ull) break;
          }
          asm volatile("" ::: "memory");
        }
        float4 P = *(const float4*)&sPK[slot][lane][0];
        float4 K = *(const float4*)&sKoT[slot][col][0];

        unsigned long long mIv;
        {
          float p = ((P.x + P.y) + P.z) + P.w;
          gI = (gI + p) * dA;
          float Ii = gI * (0.f - vI);
          float dvi = 0.5f * ((-0.1f) * (vI - (-65.f)) + Ii);
          dvi = dvi * 0.0125f + dvi * 0.9875f;
          vI = fmaxf(vI + dvi, -200.f);
          rI = rI - 1; if (rI < 0) rI = 0;
          bool canI = (rI == 0);
          bool sI = ((vI - (-50.f)) >= 0.f) && canI;
          vI = (sI || !canI) ? -65.f : vI;
          rI = sI ? 6 : rI;
          mIv = __ballot(sI);
        }

        {
          float ko = ((K.x + K.y) + K.z) + K.w;
          gO = (gO + ko) * dA;
          float Io = gO * (0.f - vO);
          float dvo = 0.25f * ((-0.05f) * (vO - (-65.f)) + Io);
          dvo = dvo * 0.0125f + dvo * 0.9875f;
          vO = fmaxf(vO + dvo, -200.f);
          rO = rO - 1; if (rO < 0) rO = 0;
          bool canO = (rO == 0);
          bool sO = ((vO - (-50.f)) >= 0.f) && canO;
          vO = (sO || !canO) ? -65.f : vO;
          rO = sO ? 12 : rO;
          accO += sO ? 1.f : 0.f;
        }

        // publish mI(t): data, compiler barrier, tag (DS in-order)
        if (lane == 0) {
          sMI[slot] = mIv;
          asm volatile("" ::: "memory");
          *((volatile unsigned*)&sMITag[slot]) = (unsigned)(t + 1);
        }
      }
    } else {
      for (int t = 0; t < T; ++t) __syncthreads();   // match fallback barrier count
    }
  }

  // ---- drain: O step T-1 over s_e(T-1) ----
  if (!wee) {
    float kd = 0.f;
    if (wav < 4) {
      unsigned long long e = mE;
      while (e) {
        const float* rb[8];
#pragma unroll
        for (int k = 0; k < 8; ++k) {
          bool v = (e != 0ull); int j = v ? (__ffsll(e) - 1) : 0; e &= (e - 1ull);
          rb[k] = v ? &sWeiO[(base64 + j) * 80] : sZeroRow;
        }
        float fr[8];
#pragma unroll
        for (int k = 0; k < 8; ++k) fr[k] = rb[k][colO];
#pragma unroll
        for (int k = 0; k < 8; ++k) kd += fr[k];
      }
    }
    __syncthreads();                 // wave4 done with all slots
    if (wav < 4 && lane < 16) sKoT[0][lane][wav] = kd;
    __syncthreads();
    if (wav == 4) {
      float4 K = *(const float4*)&sKoT[0][col][0];
      float ko = ((K.x + K.y) + K.z) + K.w;
      gO = (gO + ko) * dA;
      float Io = gO * (0.f - vO);
      float dvo = 0.25f * ((-0.05f) * (vO - (-65.f)) + Io);
      dvo = dvo * 0.0125f + dvo * 0.9875f;
      vO = fmaxf(vO + dvo, -200.f);
      rO = rO - 1; if (rO < 0) rO = 0;
      bool canO = (rO == 0);
      bool sO = ((vO - (-50.f)) >= 0.f) && canO;
      accO += sO ? 1.f : 0.f;
      if (lane < N_OUT) g_out[b * N_OUT + lane] = accO;
    }
  } else {
    float kd = 0.f;
    if (wav < 4) {
      unsigned long long e = mE;
      while (e) {
        const float* rb[4];
#pragma unroll
        for (int k = 0; k < 4; ++k) {
          bool v = (e != 0ull); int j = v ? (__ffsll(e) - 1) : 0; e &= (e - 1ull);
          rb[k] = v ? &sWeiO[(base64 + j) * 80] : sZeroRow;
        }
        float fr[4];
#pragma unroll
        for (int k = 0; k < 4; ++k) fr[k] = rb[k][colO];
#pragma unroll
        for (int k = 0; k < 4; ++k) kd += fr[k];
      }
    }
    __syncthreads();
    if (wav < 4 && lane < 16) sKoT[0][lane][wav] = kd;
    __syncthreads();
    if (wav < 4) {
      float4 K = *(const float4*)&sKoT[0][col][0];
      float ko = ((K.x + K.y) + K.z) + K.w;
      gO = (gO + ko) * dA;
      float Io = gO * (0.f - vO);
      float dvo = 0.25f * ((-0.05f) * (vO - (-65.f)) + Io);
      dvo = dvo * 0.0125f + dvo * 0.9875f;
      vO = fmaxf(vO + dvo, -200.f);
      rO = rO - 1; if (rO < 0) rO = 0;
      bool canO = (rO == 0);
      bool sO = ((vO - (-50.f)) >= 0.f) && canO;
      accO += sO ? 1.f : 0.f;
      if (wav == 0 && lane < N_OUT) g_out[b * N_OUT + lane] = accO;
    }
  }
}

extern "C" void kernel_launch(void* const* d_in, const int* in_sizes, int n_in,
                              void* d_out, int out_size, void* d_ws, size_t ws_size,
                              hipStream_t stream) {
  const float* g_in  = (const float*)d_in[0];
  const float* g_W0  = (const float*)d_in[1];
  const float* g_W1  = (const float*)d_in[2];
  const float* g_Wee = (const float*)d_in[3];
  const float* g_Wei = (const float*)d_in[4];
  const float* g_Wie = (const float*)d_in[5];
  float* out = (float*)d_out;
  int T = in_sizes[0] / (BB * N_IN);
  float dA = (float)exp(-0.25 / 2.0);   // tau_ampa = 2.0
  float dG = (float)exp(-0.25 / 9.0);   // tau_gaba = 9.0
  ping_kernel<<<dim3(BB), dim3(320), 0, stream>>>(g_in, g_W0, g_W1, g_Wee, g_Wei, g_Wie, out, T, dA, dG);
}